// Round 1
// baseline (561.900 us; speedup 1.0000x reference)
//
#include <hip/hip_runtime.h>
#include <hip/hip_bf16.h>

typedef __attribute__((ext_vector_type(8))) __bf16 bf16x8;
typedef __attribute__((ext_vector_type(4))) __bf16 bf16x4;
typedef __attribute__((ext_vector_type(4))) float f32x4;

#define LOG2E 1.4426950408889634f

static __device__ __forceinline__ f32x4 mfma16(bf16x8 a, bf16x8 b, f32x4 c) {
  return __builtin_amdgcn_mfma_f32_16x16x32_bf16(a, b, c, 0, 0, 0);
}

// ---------------- f32 -> bf16 convert (vectorized) ----------------
__global__ __launch_bounds__(256) void k_cvt(const float* __restrict__ in,
                                             __bf16* __restrict__ out, int n4) {
  for (int i = blockIdx.x * blockDim.x + threadIdx.x; i < n4;
       i += gridDim.x * blockDim.x) {
    float4 v = reinterpret_cast<const float4*>(in)[i];
    bf16x4 o = {(__bf16)v.x, (__bf16)v.y, (__bf16)v.z, (__bf16)v.w};
    reinterpret_cast<bf16x4*>(out)[i] = o;
  }
}

// ---------------- weight convert + transpose: Wt[n][k] = W[k][n] ----------------
__global__ __launch_bounds__(256) void k_wt(const float* __restrict__ W,
                                            __bf16* __restrict__ Wt) {
  __shared__ float tile[64][65];
  int bx = blockIdx.x;  // n-tile
  int by = blockIdx.y;  // k-tile
  int tid = threadIdx.x;
#pragma unroll
  for (int p = 0; p < 16; p++) {
    int idx = p * 256 + tid;
    int r = idx >> 6, c = idx & 63;
    tile[r][c] = W[(size_t)(by * 64 + r) * 512 + bx * 64 + c];
  }
  __syncthreads();
#pragma unroll
  for (int p = 0; p < 16; p++) {
    int idx = p * 256 + tid;
    int rn = idx >> 6, ck = idx & 63;
    Wt[(size_t)(bx * 64 + rn) * 512 + by * 64 + ck] = (__bf16)tile[ck][rn];
  }
}

// ---------------- GEMM: C[M,512] = A[M,512](bf16) @ W (via Wt[n][k] bf16) ----------------
// OUT_MODE 0: write bf16 to head-layout [B,H,S,64], scaled
// OUT_MODE 1: write f32 row-major [M,512]
template <int OUT_MODE>
__global__ __launch_bounds__(256) void k_gemm(const __bf16* __restrict__ A,
                                              const __bf16* __restrict__ Bt,
                                              void* __restrict__ Cout,
                                              float scale) {
  __shared__ __bf16 As[128][72];  // BM=128, BK=64, +8 pad
  __shared__ __bf16 Bs[64][72];   // BN=64 rows (n), BK=64 cols (k), +8 pad
  const int tid = threadIdx.x;
  const int wid = tid >> 6, lane = tid & 63;
  const int g = lane >> 4, c = lane & 15;
  const int m0 = blockIdx.x * 128, n0 = blockIdx.y * 64;
  const int wr = wid >> 1, wc = wid & 1;  // 2x2 wave grid: 64x32 per wave

  f32x4 acc[4][2];
#pragma unroll
  for (int i = 0; i < 4; i++)
#pragma unroll
    for (int j = 0; j < 2; j++) acc[i][j] = (f32x4){0.f, 0.f, 0.f, 0.f};

  for (int k0 = 0; k0 < 512; k0 += 64) {
#pragma unroll
    for (int q = 0; q < 4; q++) {
      int idx = (q * 256 + tid) * 8;
      int r = idx >> 6, cc = idx & 63;
      bf16x8 v = *reinterpret_cast<const bf16x8*>(A + (size_t)(m0 + r) * 512 + k0 + cc);
      *reinterpret_cast<bf16x8*>(&As[r][cc]) = v;
    }
#pragma unroll
    for (int q = 0; q < 2; q++) {
      int idx = (q * 256 + tid) * 8;
      int r = idx >> 6, cc = idx & 63;
      bf16x8 v = *reinterpret_cast<const bf16x8*>(Bt + (size_t)(n0 + r) * 512 + k0 + cc);
      *reinterpret_cast<bf16x8*>(&Bs[r][cc]) = v;
    }
    __syncthreads();
#pragma unroll
    for (int kk = 0; kk < 2; kk++) {
      bf16x8 bfrag[2];
#pragma unroll
      for (int nf = 0; nf < 2; nf++)
        bfrag[nf] = *reinterpret_cast<const bf16x8*>(&Bs[wc * 32 + nf * 16 + c][kk * 32 + g * 8]);
#pragma unroll
      for (int mf = 0; mf < 4; mf++) {
        bf16x8 afrag = *reinterpret_cast<const bf16x8*>(&As[wr * 64 + mf * 16 + c][kk * 32 + g * 8]);
#pragma unroll
        for (int nf = 0; nf < 2; nf++)
          acc[mf][nf] = mfma16(afrag, bfrag[nf], acc[mf][nf]);
      }
    }
    __syncthreads();
  }
  // epilogue: C/D layout row=g*4+r, col=c (verified)
#pragma unroll
  for (int mf = 0; mf < 4; mf++)
#pragma unroll
    for (int nf = 0; nf < 2; nf++)
#pragma unroll
      for (int r = 0; r < 4; r++) {
        int mm = m0 + wr * 64 + mf * 16 + g * 4 + r;
        int nn = n0 + wc * 32 + nf * 16 + c;
        float val = acc[mf][nf][r] * scale;
        if (OUT_MODE == 0) {
          int b = mm >> 12, s = mm & 4095, h = nn >> 6, d = nn & 63;
          ((__bf16*)Cout)[((((size_t)b * 8 + h) * 4096) + s) * 64 + d] = (__bf16)val;
        } else {
          ((float*)Cout)[(size_t)mm * 512 + nn] = val;
        }
      }
}

// ---------------- V transpose: Vt[bh][d][s] = V[bh][s][d] ----------------
__global__ __launch_bounds__(256) void k_vt(const __bf16* __restrict__ V,
                                            __bf16* __restrict__ Vt) {
  __shared__ __bf16 t[64][72];
  int bh = blockIdx.y;
  int s0 = blockIdx.x * 64;
  const __bf16* Vp = V + (size_t)bh * 4096 * 64;
  __bf16* Vtp = Vt + (size_t)bh * 64 * 4096;
  int tid = threadIdx.x;
#pragma unroll
  for (int p = 0; p < 2; p++) {
    int idx = (p * 256 + tid) * 8;
    int r = idx >> 6, cc = idx & 63;
    *reinterpret_cast<bf16x8*>(&t[r][cc]) =
        *reinterpret_cast<const bf16x8*>(Vp + (size_t)(s0 + r) * 64 + cc);
  }
  __syncthreads();
#pragma unroll
  for (int p = 0; p < 2; p++) {
    int idx = (p * 256 + tid) * 8;
    int d = idx >> 6, ss = idx & 63;
    __bf16 tmp[8];
#pragma unroll
    for (int j = 0; j < 8; j++) tmp[j] = t[ss + j][d];
    *reinterpret_cast<bf16x8*>(Vtp + (size_t)d * 4096 + s0 + ss) =
        *reinterpret_cast<bf16x8*>(tmp);
  }
}

// ---------------- flash attention ----------------
// grid: x = S/64 q-blocks, y = B*H. 4 waves, 16 q-rows each. KB=64.
__global__ __launch_bounds__(256) void k_attn(const __bf16* __restrict__ Q,
                                              const __bf16* __restrict__ K,
                                              const __bf16* __restrict__ Vt,
                                              const float* __restrict__ bias,
                                              __bf16* __restrict__ Out) {
  const int bh = blockIdx.y, b = bh >> 3, h = bh & 7;
  const int qb = blockIdx.x;
  const int tid = threadIdx.x, wid = tid >> 6, lane = tid & 63;
  const int g = lane >> 4, c = lane & 15;
  const __bf16* Qh = Q + (size_t)bh * 4096 * 64;
  const __bf16* Kh = K + (size_t)bh * 4096 * 64;
  const __bf16* Vh = Vt + (size_t)bh * 64 * 4096;
  const int q0 = qb * 64 + wid * 16;       // wave's 16 q rows
  const int qrow_base = q0 + g * 4;        // this lane's 4 rows: +r

  __shared__ __bf16 Pl[4][16][72];  // per-wave P tile, padded

  // Q fragments (hd = 64 -> 2 k-groups), A-map: a[i] = Q[q0+c][kk*32 + g*8 + i]
  bf16x8 qa[2];
  qa[0] = *reinterpret_cast<const bf16x8*>(Qh + (size_t)(q0 + c) * 64 + g * 8);
  qa[1] = *reinterpret_cast<const bf16x8*>(Qh + (size_t)(q0 + c) * 64 + 32 + g * 8);

  float m_run[4], l_run[4];
  f32x4 o[4];
#pragma unroll
  for (int r = 0; r < 4; r++) { m_run[r] = -1e30f; l_run[r] = 0.f; }
#pragma unroll
  for (int f = 0; f < 4; f++) o[f] = (f32x4){0.f, 0.f, 0.f, 0.f};

  for (int kc = 0; kc < 4096; kc += 64) {
    // ---- S = Q @ K^T  (4 key-fragments of 16) ----
    f32x4 st[4];
#pragma unroll
    for (int f = 0; f < 4; f++) {
      int n0 = kc + f * 16;
      bf16x8 kb0 = *reinterpret_cast<const bf16x8*>(Kh + (size_t)(n0 + c) * 64 + g * 8);
      bf16x8 kb1 = *reinterpret_cast<const bf16x8*>(Kh + (size_t)(n0 + c) * 64 + 32 + g * 8);
      f32x4 z = (f32x4){0.f, 0.f, 0.f, 0.f};
      f32x4 s = mfma16(qa[0], kb0, z);
      st[f] = mfma16(qa[1], kb1, s);
    }
    // ---- add bias (f32, absolute addressed) ----
#pragma unroll
    for (int f = 0; f < 4; f++)
#pragma unroll
      for (int r = 0; r < 4; r++)
        st[f][r] += bias[(size_t)(qrow_base + r) * 4096 + kc + f * 16 + c];

    // ---- online softmax ----
    float p[4][4];  // [f][r]
#pragma unroll
    for (int r = 0; r < 4; r++) {
      float mx = fmaxf(fmaxf(st[0][r], st[1][r]), fmaxf(st[2][r], st[3][r]));
#pragma unroll
      for (int off = 1; off < 16; off <<= 1) mx = fmaxf(mx, __shfl_xor(mx, off));
      float mnew = fmaxf(m_run[r], mx);
      float alpha = __builtin_exp2f((m_run[r] - mnew) * LOG2E);
      float sum = 0.f;
#pragma unroll
      for (int f = 0; f < 4; f++) {
        float pv = __builtin_exp2f((st[f][r] - mnew) * LOG2E);
        p[f][r] = pv;
        sum += pv;
      }
#pragma unroll
      for (int off = 1; off < 16; off <<= 1) sum += __shfl_xor(sum, off);
      l_run[r] = l_run[r] * alpha + sum;
      m_run[r] = mnew;
#pragma unroll
      for (int f = 0; f < 4; f++) o[f][r] *= alpha;
    }
    // ---- P -> LDS (C-layout positions, absolute) ----
#pragma unroll
    for (int f = 0; f < 4; f++)
#pragma unroll
      for (int r = 0; r < 4; r++)
        Pl[wid][g * 4 + r][f * 16 + c] = (__bf16)p[f][r];

    // ---- O += P @ V  ----
#pragma unroll
    for (int kk = 0; kk < 2; kk++) {
      bf16x8 pa = *reinterpret_cast<const bf16x8*>(&Pl[wid][c][kk * 32 + g * 8]);
#pragma unroll
      for (int f = 0; f < 4; f++) {
        bf16x8 vb = *reinterpret_cast<const bf16x8*>(
            Vh + (size_t)(f * 16 + c) * 4096 + kc + kk * 32 + g * 8);
        o[f] = mfma16(pa, vb, o[f]);
      }
    }
  }

  // ---- normalize + store to [B,S,H*64] (row-major 8192x512) ----
#pragma unroll
  for (int f = 0; f < 4; f++)
#pragma unroll
    for (int r = 0; r < 4; r++) {
      float val = o[f][r] / l_run[r];
      int srow = qrow_base + r;
      int d = f * 16 + c;
      Out[((size_t)b * 4096 + srow) * 512 + h * 64 + d] = (__bf16)val;
    }
}

// ---------------- launch ----------------
extern "C" void kernel_launch(void* const* d_in, const int* in_sizes, int n_in,
                              void* d_out, int out_size, void* d_ws, size_t ws_size,
                              hipStream_t stream) {
  const float* xq = (const float*)d_in[0];
  const float* xm = (const float*)d_in[1];
  const float* bias = (const float*)d_in[2];
  const float* Wq = (const float*)d_in[3];
  const float* Wk = (const float*)d_in[4];
  const float* Wv = (const float*)d_in[5];
  const float* Wo = (const float*)d_in[6];

  const size_t MB = 1024 * 1024;
  char* ws = (char*)d_ws;
  __bf16* xq_b = (__bf16*)(ws + 0);         // 8 MB
  __bf16* xm_b = (__bf16*)(ws + 8 * MB);    // 8 MB
  __bf16* wqt = (__bf16*)(ws + 16 * MB);    // 512 KB each
  __bf16* wkt = (__bf16*)(ws + 16 * MB + 524288);
  __bf16* wvt = (__bf16*)(ws + 17 * MB);
  __bf16* wot = (__bf16*)(ws + 17 * MB + 524288);
  __bf16* Qb = (__bf16*)(ws + 18 * MB);     // 8 MB [B,H,S,64]
  __bf16* Kb = (__bf16*)(ws + 26 * MB);     // 8 MB
  __bf16* Vb = (__bf16*)(ws + 34 * MB);     // 8 MB
  __bf16* Vtb = (__bf16*)(ws + 42 * MB);    // 8 MB [B,H,64,S]
  __bf16* AOb = (__bf16*)(ws + 50 * MB);    // 8 MB [B,S,512]
  if (ws_size < 58 * MB) return;  // need 58 MB scratch

  const int n4 = 8192 * 512 / 4;
  k_cvt<<<2048, 256, 0, stream>>>(xq, xq_b, n4);
  k_cvt<<<2048, 256, 0, stream>>>(xm, xm_b, n4);
  k_wt<<<dim3(8, 8), 256, 0, stream>>>(Wq, wqt);
  k_wt<<<dim3(8, 8), 256, 0, stream>>>(Wk, wkt);
  k_wt<<<dim3(8, 8), 256, 0, stream>>>(Wv, wvt);
  k_wt<<<dim3(8, 8), 256, 0, stream>>>(Wo, wot);

  k_gemm<0><<<dim3(64, 8), 256, 0, stream>>>(xq_b, wqt, Qb, 0.125f);
  k_gemm<0><<<dim3(64, 8), 256, 0, stream>>>(xm_b, wkt, Kb, 1.0f);
  k_gemm<0><<<dim3(64, 8), 256, 0, stream>>>(xm_b, wvt, Vb, 1.0f);

  k_vt<<<dim3(64, 16), 256, 0, stream>>>(Vb, Vtb);

  k_attn<<<dim3(64, 16), 256, 0, stream>>>(Qb, Kb, Vtb, bias, AOb);

  k_gemm<1><<<dim3(64, 8), 256, 0, stream>>>(AOb, wot, d_out, 1.0f);
}